// Round 3
// baseline (104.690 us; speedup 1.0000x reference)
//
#include <hip/hip_runtime.h>
#include <hip/hip_cooperative_groups.h>
#include <math.h>

namespace cg = cooperative_groups;

#define LL 500
#define BB 4
#define EE 100000
#define NBINS 24
#define TOTAL (BB * EE)
#define BLOCK 256
#define NBLOCKS 512

struct f3 { float x, y, z; };

__device__ __forceinline__ f3 ld3(const float* __restrict__ p) {
    f3 r; r.x = p[0]; r.y = p[1]; r.z = p[2]; return r;
}
__device__ __forceinline__ f3 sub3(f3 a, f3 b) {
    f3 r; r.x = a.x - b.x; r.y = a.y - b.y; r.z = a.z - b.z; return r;
}
__device__ __forceinline__ f3 cross3(f3 a, f3 b) {
    f3 r;
    r.x = a.y * b.z - a.z * b.y;
    r.y = a.z * b.x - a.x * b.z;
    r.z = a.x * b.y - a.y * b.x;
    return r;
}
__device__ __forceinline__ float dot3(f3 a, f3 b) {
    return fmaf(a.x, b.x, fmaf(a.y, b.y, a.z * b.z));
}

__device__ __forceinline__ float theta_val(
    const float* __restrict__ N,  const float* __restrict__ CA,
    const float* __restrict__ CB, const float* __restrict__ coeff,
    const int* __restrict__ x_idx, const int* __restrict__ y_idx, int i)
{
    const int e = i >> 2;       // edge index
    const int b = i & 3;        // batch index (adjacent lanes share edge)
    const int x = x_idx[e];
    const int y = y_idx[e];

    const float* Nb  = N  + b * (LL * 3);
    const float* CAb = CA + b * (LL * 3);
    const float* CBb = CB + b * (LL * 3);

    const f3 xN  = ld3(Nb  + 3 * x);
    const f3 xCA = ld3(CAb + 3 * x);
    const f3 xCB = ld3(CBb + 3 * x);
    const f3 yCB = ld3(CBb + 3 * y);

    const f3 b1 = sub3(xCA, xN);
    const f3 b2 = sub3(xCB, xCA);
    const f3 b3 = sub3(yCB, xCB);

    const f3 n1 = cross3(b1, b2);
    const f3 n2 = cross3(b2, b3);

    // dot(cross(n1, b2u), n2) = dot(cross(n1,b2), n2) / ||b2||
    const float rn = rsqrtf(dot3(b2, b2));
    const f3 m = cross3(n1, b2);
    const float s = dot3(m, n2) * rn;
    const float c = dot3(n1, n2);

    const float theta = atan2f(s, c);

    const float step  = 0.261799387799149436f;      // 15 * pi / 180
    const float c0    = -3.14159265358979324f + 0.5f * step;
    const float twoPi = 6.28318530717958648f;

    const float tw = (theta < c0) ? theta + twoPi : theta;

    int seg = (int)floorf((tw - c0) / step);
    seg = seg < 0 ? 0 : (seg > NBINS - 1 ? NBINS - 1 : seg);

    const float t = tw - (c0 + (float)seg * step);

    const float4 cs = *reinterpret_cast<const float4*>(
        coeff + (((size_t)x * LL + (size_t)y) * NBINS + (size_t)seg) * 4);

    return fmaf(fmaf(fmaf(cs.w, t, cs.z), t, cs.y), t, cs.x);
}

__global__ void __launch_bounds__(BLOCK) theta_coop_kernel(
    const float* __restrict__ N,
    const float* __restrict__ CA,
    const float* __restrict__ CB,
    const float* __restrict__ coeff,
    const int* __restrict__ x_idx,
    const int* __restrict__ y_idx,
    float* __restrict__ partials,
    float* __restrict__ out)
{
    float acc = 0.0f;
    const int stride = NBLOCKS * BLOCK;
    for (int i = blockIdx.x * BLOCK + threadIdx.x; i < TOTAL; i += stride)
        acc += theta_val(N, CA, CB, coeff, x_idx, y_idx, i);

    // wave64 reduction
    #pragma unroll
    for (int off = 32; off > 0; off >>= 1)
        acc += __shfl_down(acc, off, 64);

    __shared__ float wsum[BLOCK / 64];
    const int lane = threadIdx.x & 63;
    const int wid  = threadIdx.x >> 6;
    if (lane == 0) wsum[wid] = acc;
    __syncthreads();
    if (threadIdx.x == 0)
        partials[blockIdx.x] = wsum[0] + wsum[1] + wsum[2] + wsum[3];

    __threadfence();            // device-scope release of partials
    cg::this_grid().sync();     // grid-wide barrier (cooperative launch)

    if (blockIdx.x == 0) {
        float v = 0.0f;
        for (int i = threadIdx.x; i < NBLOCKS; i += BLOCK)
            v += partials[i];

        #pragma unroll
        for (int off = 32; off > 0; off >>= 1)
            v += __shfl_down(v, off, 64);

        __shared__ float wsum2[BLOCK / 64];
        if (lane == 0) wsum2[wid] = v;
        __syncthreads();
        if (threadIdx.x == 0)
            out[0] = wsum2[0] + wsum2[1] + wsum2[2] + wsum2[3];
    }
}

extern "C" void kernel_launch(void* const* d_in, const int* in_sizes, int n_in,
                              void* d_out, int out_size, void* d_ws, size_t ws_size,
                              hipStream_t stream) {
    const float* N     = (const float*)d_in[0];
    const float* CA    = (const float*)d_in[1];
    const float* CB    = (const float*)d_in[2];
    const float* coeff = (const float*)d_in[3];
    const int* x_idx   = (const int*)d_in[4];
    const int* y_idx   = (const int*)d_in[5];
    float* out      = (float*)d_out;
    float* partials = (float*)d_ws;   // NBLOCKS floats, write-before-read each call

    void* args[] = { (void*)&N, (void*)&CA, (void*)&CB, (void*)&coeff,
                     (void*)&x_idx, (void*)&y_idx, (void*)&partials, (void*)&out };

    hipLaunchCooperativeKernel((const void*)theta_coop_kernel,
                               dim3(NBLOCKS), dim3(BLOCK),
                               args, 0, stream);
}

// Round 4
// 16.246 us; speedup vs baseline: 6.4442x; 6.4442x over previous
//
#include <hip/hip_runtime.h>
#include <math.h>

#define LL 500
#define BB 4
#define EE 100000
#define NBINS 24
#define TOTAL (BB * EE)
#define HALF (TOTAL / 2)                  // 200000, divisible by 4
#define BLOCK 256
#define GRID1 ((HALF + BLOCK - 1) / BLOCK)  // 782
#define GRID2 1

struct f3 { float x, y, z; };

__device__ __forceinline__ f3 ld3(const float* __restrict__ p) {
    f3 r; r.x = p[0]; r.y = p[1]; r.z = p[2]; return r;
}
__device__ __forceinline__ f3 sub3(f3 a, f3 b) {
    f3 r; r.x = a.x - b.x; r.y = a.y - b.y; r.z = a.z - b.z; return r;
}
__device__ __forceinline__ f3 cross3(f3 a, f3 b) {
    f3 r;
    r.x = a.y * b.z - a.z * b.y;
    r.y = a.z * b.x - a.x * b.z;
    r.z = a.x * b.y - a.y * b.x;
    return r;
}
__device__ __forceinline__ float dot3(f3 a, f3 b) {
    return fmaf(a.x, b.x, fmaf(a.y, b.y, a.z * b.z));
}

__device__ __forceinline__ float theta_val(
    const float* __restrict__ N,  const float* __restrict__ CA,
    const float* __restrict__ CB, const float* __restrict__ coeff,
    const int* __restrict__ x_idx, const int* __restrict__ y_idx, int i)
{
    const int e = i >> 2;       // edge index
    const int b = i & 3;        // batch index (adjacent lanes share edge)
    const int x = x_idx[e];
    const int y = y_idx[e];

    const float* Nb  = N  + b * (LL * 3);
    const float* CAb = CA + b * (LL * 3);
    const float* CBb = CB + b * (LL * 3);

    const f3 xN  = ld3(Nb  + 3 * x);
    const f3 xCA = ld3(CAb + 3 * x);
    const f3 xCB = ld3(CBb + 3 * x);
    const f3 yCB = ld3(CBb + 3 * y);

    const f3 b1 = sub3(xCA, xN);
    const f3 b2 = sub3(xCB, xCA);
    const f3 b3 = sub3(yCB, xCB);

    const f3 n1 = cross3(b1, b2);
    const f3 n2 = cross3(b2, b3);

    // dot(cross(n1, b2u), n2) = dot(cross(n1,b2), n2) / ||b2||
    const float rn = rsqrtf(dot3(b2, b2));
    const f3 m = cross3(n1, b2);
    const float s = dot3(m, n2) * rn;
    const float c = dot3(n1, n2);

    const float theta = atan2f(s, c);

    const float step  = 0.261799387799149436f;      // 15 * pi / 180
    const float c0    = -3.14159265358979324f + 0.5f * step;
    const float twoPi = 6.28318530717958648f;

    const float tw = (theta < c0) ? theta + twoPi : theta;

    int seg = (int)floorf((tw - c0) / step);
    seg = seg < 0 ? 0 : (seg > NBINS - 1 ? NBINS - 1 : seg);

    const float t = tw - (c0 + (float)seg * step);

    const float4 cs = *reinterpret_cast<const float4*>(
        coeff + (((size_t)x * LL + (size_t)y) * NBINS + (size_t)seg) * 4);

    return fmaf(fmaf(fmaf(cs.w, t, cs.z), t, cs.y), t, cs.x);
}

__global__ void __launch_bounds__(BLOCK) theta_partial_kernel(
    const float* __restrict__ N,
    const float* __restrict__ CA,
    const float* __restrict__ CB,
    const float* __restrict__ coeff,
    const int* __restrict__ x_idx,
    const int* __restrict__ y_idx,
    float* __restrict__ partials)
{
    const int tid = blockIdx.x * BLOCK + threadIdx.x;
    float val = 0.0f;
    if (tid < HALF) {
        // two independent chains per thread -> 2 gathers in flight (ILP)
        const float v0 = theta_val(N, CA, CB, coeff, x_idx, y_idx, tid);
        const float v1 = theta_val(N, CA, CB, coeff, x_idx, y_idx, tid + HALF);
        val = v0 + v1;
    }

    // wave64 reduction
    #pragma unroll
    for (int off = 32; off > 0; off >>= 1)
        val += __shfl_down(val, off, 64);

    __shared__ float wsum[BLOCK / 64];
    const int lane = threadIdx.x & 63;
    const int wid  = threadIdx.x >> 6;
    if (lane == 0) wsum[wid] = val;
    __syncthreads();
    if (threadIdx.x == 0)
        partials[blockIdx.x] = wsum[0] + wsum[1] + wsum[2] + wsum[3];
}

__global__ void __launch_bounds__(BLOCK) theta_reduce_kernel(
    const float* __restrict__ partials,
    float* __restrict__ out)
{
    float v = 0.0f;
    for (int i = threadIdx.x; i < GRID1; i += BLOCK)
        v += partials[i];

    #pragma unroll
    for (int off = 32; off > 0; off >>= 1)
        v += __shfl_down(v, off, 64);

    __shared__ float wsum[BLOCK / 64];
    const int lane = threadIdx.x & 63;
    const int wid  = threadIdx.x >> 6;
    if (lane == 0) wsum[wid] = v;
    __syncthreads();
    if (threadIdx.x == 0)
        out[0] = wsum[0] + wsum[1] + wsum[2] + wsum[3];
}

extern "C" void kernel_launch(void* const* d_in, const int* in_sizes, int n_in,
                              void* d_out, int out_size, void* d_ws, size_t ws_size,
                              hipStream_t stream) {
    const float* N     = (const float*)d_in[0];
    const float* CA    = (const float*)d_in[1];
    const float* CB    = (const float*)d_in[2];
    const float* coeff = (const float*)d_in[3];
    const int* x_idx   = (const int*)d_in[4];
    const int* y_idx   = (const int*)d_in[5];
    float* out      = (float*)d_out;
    float* partials = (float*)d_ws;   // GRID1 floats, write-before-read each call

    theta_partial_kernel<<<GRID1, BLOCK, 0, stream>>>(N, CA, CB, coeff,
                                                      x_idx, y_idx, partials);
    theta_reduce_kernel<<<GRID2, BLOCK, 0, stream>>>(partials, out);
}

// Round 5
// 14.044 us; speedup vs baseline: 7.4545x; 1.1568x over previous
//
#include <hip/hip_runtime.h>
#include <math.h>

#define LL 500
#define BB 4
#define EE 100000
#define NBINS 24
#define TOTAL (BB * EE)
#define BLOCK 256
#define NB1 512                      // 2 blocks/CU (72KB LDS each)
#define COORD_F (BB * LL * 3)        // 6000 floats per array

struct f3 { float x, y, z; };

__device__ __forceinline__ f3 ld3(const float* __restrict__ p) {
    f3 r; r.x = p[0]; r.y = p[1]; r.z = p[2]; return r;
}
__device__ __forceinline__ f3 sub3(f3 a, f3 b) {
    f3 r; r.x = a.x - b.x; r.y = a.y - b.y; r.z = a.z - b.z; return r;
}
__device__ __forceinline__ f3 cross3(f3 a, f3 b) {
    f3 r;
    r.x = a.y * b.z - a.z * b.y;
    r.y = a.z * b.x - a.x * b.z;
    r.z = a.x * b.y - a.y * b.x;
    return r;
}
__device__ __forceinline__ float dot3(f3 a, f3 b) {
    return fmaf(a.x, b.x, fmaf(a.y, b.y, a.z * b.z));
}

__global__ void __launch_bounds__(BLOCK) theta_partial_kernel(
    const float* __restrict__ N,
    const float* __restrict__ CA,
    const float* __restrict__ CB,
    const float* __restrict__ coeff,
    const int* __restrict__ x_idx,
    const int* __restrict__ y_idx,
    float* __restrict__ partials)
{
    // Stage all coords in LDS: [N | CA | CB], each (B,L,3) = 6000 floats.
    __shared__ float lds[3 * COORD_F];   // 72 KB
    {
        const float4* s0 = reinterpret_cast<const float4*>(N);
        const float4* s1 = reinterpret_cast<const float4*>(CA);
        const float4* s2 = reinterpret_cast<const float4*>(CB);
        float4* d0 = reinterpret_cast<float4*>(&lds[0]);
        float4* d1 = reinterpret_cast<float4*>(&lds[COORD_F]);
        float4* d2 = reinterpret_cast<float4*>(&lds[2 * COORD_F]);
        for (int j = threadIdx.x; j < COORD_F / 4; j += BLOCK) {
            d0[j] = s0[j];
            d1[j] = s1[j];
            d2[j] = s2[j];
        }
    }
    __syncthreads();

    const float step  = 0.261799387799149436f;      // 15 * pi / 180
    const float c0    = -3.14159265358979324f + 0.5f * step;
    const float twoPi = 6.28318530717958648f;

    float acc = 0.0f;
    for (int i = blockIdx.x * BLOCK + threadIdx.x; i < TOTAL; i += NB1 * BLOCK) {
        const int e = i >> 2;       // edge index
        const int b = i & 3;        // batch (adjacent lanes share edge -> gather clusters)
        const int x = x_idx[e];
        const int y = y_idx[e];

        const float* Nb  = &lds[b * (LL * 3)];
        const float* CAb = &lds[COORD_F + b * (LL * 3)];
        const float* CBb = &lds[2 * COORD_F + b * (LL * 3)];

        const f3 xN  = ld3(Nb  + 3 * x);
        const f3 xCA = ld3(CAb + 3 * x);
        const f3 xCB = ld3(CBb + 3 * x);
        const f3 yCB = ld3(CBb + 3 * y);

        const f3 b1 = sub3(xCA, xN);
        const f3 b2 = sub3(xCB, xCA);
        const f3 b3 = sub3(yCB, xCB);

        const f3 n1 = cross3(b1, b2);
        const f3 n2 = cross3(b2, b3);

        // dot(cross(n1, b2u), n2) = dot(cross(n1,b2), n2) / ||b2||
        const float rn = rsqrtf(dot3(b2, b2));
        const f3 m = cross3(n1, b2);
        const float s = dot3(m, n2) * rn;
        const float c = dot3(n1, n2);

        const float theta = atan2f(s, c);

        const float tw = (theta < c0) ? theta + twoPi : theta;

        int seg = (int)floorf((tw - c0) / step);
        seg = seg < 0 ? 0 : (seg > NBINS - 1 ? NBINS - 1 : seg);

        const float t = tw - (c0 + (float)seg * step);

        const float4 cs = *reinterpret_cast<const float4*>(
            coeff + (((size_t)x * LL + (size_t)y) * NBINS + (size_t)seg) * 4);

        acc += fmaf(fmaf(fmaf(cs.w, t, cs.z), t, cs.y), t, cs.x);
    }

    // wave64 reduction
    #pragma unroll
    for (int off = 32; off > 0; off >>= 1)
        acc += __shfl_down(acc, off, 64);

    __shared__ float wsum[BLOCK / 64];
    const int lane = threadIdx.x & 63;
    const int wid  = threadIdx.x >> 6;
    if (lane == 0) wsum[wid] = acc;
    __syncthreads();
    if (threadIdx.x == 0)
        partials[blockIdx.x] = wsum[0] + wsum[1] + wsum[2] + wsum[3];
}

__global__ void __launch_bounds__(BLOCK) theta_reduce_kernel(
    const float* __restrict__ partials,
    float* __restrict__ out)
{
    // NB1 = 512 partials, 256 threads -> 2 each
    float v = partials[threadIdx.x] + partials[threadIdx.x + BLOCK];

    #pragma unroll
    for (int off = 32; off > 0; off >>= 1)
        v += __shfl_down(v, off, 64);

    __shared__ float wsum[BLOCK / 64];
    const int lane = threadIdx.x & 63;
    const int wid  = threadIdx.x >> 6;
    if (lane == 0) wsum[wid] = v;
    __syncthreads();
    if (threadIdx.x == 0)
        out[0] = wsum[0] + wsum[1] + wsum[2] + wsum[3];
}

extern "C" void kernel_launch(void* const* d_in, const int* in_sizes, int n_in,
                              void* d_out, int out_size, void* d_ws, size_t ws_size,
                              hipStream_t stream) {
    const float* N     = (const float*)d_in[0];
    const float* CA    = (const float*)d_in[1];
    const float* CB    = (const float*)d_in[2];
    const float* coeff = (const float*)d_in[3];
    const int* x_idx   = (const int*)d_in[4];
    const int* y_idx   = (const int*)d_in[5];
    float* out      = (float*)d_out;
    float* partials = (float*)d_ws;   // NB1 floats, write-before-read each call

    theta_partial_kernel<<<NB1, BLOCK, 0, stream>>>(N, CA, CB, coeff,
                                                    x_idx, y_idx, partials);
    theta_reduce_kernel<<<1, BLOCK, 0, stream>>>(partials, out);
}